// Round 1
// baseline (1534.080 us; speedup 1.0000x reference)
//
#include <hip/hip_runtime.h>

#define NN 50000
#define NE 1600000
#define CLAMP_V 5.0f

__global__ __launch_bounds__(256) void proj_kernel(
    const float* __restrict__ x,
    const float* __restrict__ WQ, const float* __restrict__ bQ,
    const float* __restrict__ WK, const float* __restrict__ WVw,
    float* __restrict__ Q, float* __restrict__ K, float* __restrict__ V)
{
    __shared__ float sWQ[4096], sWK[4096], sWV[4096];
    for (int i = threadIdx.x; i < 4096; i += 256) {
        sWQ[i] = WQ[i]; sWK[i] = WK[i]; sWV[i] = WVw[i];
    }
    __syncthreads();
    const int col = threadIdx.x & 63;
    const int nl  = threadIdx.x >> 6;
    const float bq = bQ[col];
    for (int node = blockIdx.x * 4 + nl; node < NN; node += gridDim.x * 4) {
        const float* xr = x + (size_t)node * 64;
        float aq = 0.f, ak = 0.f, av = 0.f;
        #pragma unroll
        for (int j = 0; j < 64; ++j) {
            float xv = xr[j];
            aq = fmaf(xv, sWQ[j*64+col], aq);
            ak = fmaf(xv, sWK[j*64+col], ak);
            av = fmaf(xv, sWV[j*64+col], av);
        }
        Q[(size_t)node*64+col] = aq + bq;
        K[(size_t)node*64+col] = ak;
        V[(size_t)node*64+col] = av;
    }
}

__global__ __launch_bounds__(256) void edge_kernel(
    const float* __restrict__ edge_attr,
    const float* __restrict__ WE1, const float* __restrict__ bE1,
    const int* __restrict__ ei,
    const float* __restrict__ Q, const float* __restrict__ K,
    float* __restrict__ wE, float* __restrict__ den)
{
    __shared__ float sW[4096];
    for (int i = threadIdx.x; i < 4096; i += 256) sW[i] = WE1[i];
    __syncthreads();
    const int lane   = threadIdx.x & 63;
    const int waveId = (blockIdx.x * 256 + threadIdx.x) >> 6;
    const int nWaves = (gridDim.x * 256) >> 6;
    const float bias = bE1[lane];
    const float inv_sqrt8 = 0.35355339059327373f;
    for (int e = waveId; e < NE; e += nWaves) {
        float ea = edge_attr[(size_t)e * 64 + lane];
        float acc = bias;
        #pragma unroll
        for (int j = 0; j < 64; ++j) {
            acc = fmaf(__shfl(ea, j), sW[j*64 + lane], acc);
        }
        int src = ei[e], dst = ei[NE + e];
        float sc = K[(size_t)src*64 + lane] * Q[(size_t)dst*64 + lane] * acc;
        wE[(size_t)e * 64 + lane] = sc;
        // per-head (8-lane) sum
        float ssum = sc;
        ssum += __shfl_xor(ssum, 1);
        ssum += __shfl_xor(ssum, 2);
        ssum += __shfl_xor(ssum, 4);
        float s = ssum * inv_sqrt8;
        s = fminf(fmaxf(s, -CLAMP_V), CLAMP_V);
        float ex = __expf(s);
        if ((lane & 7) == 0) {
            atomicAdd(&den[dst * 8 + (lane >> 3)], ex);
        }
    }
}

__global__ __launch_bounds__(256) void agg_kernel(
    const float* __restrict__ wE,
    const int* __restrict__ ei,
    const float* __restrict__ V,
    const float* __restrict__ den,
    float* __restrict__ wV)
{
    const int lane   = threadIdx.x & 63;
    const int waveId = (blockIdx.x * 256 + threadIdx.x) >> 6;
    const int nWaves = (gridDim.x * 256) >> 6;
    const float inv_sqrt8 = 0.35355339059327373f;
    for (int e = waveId; e < NE; e += nWaves) {
        float sc = wE[(size_t)e * 64 + lane];
        int src = ei[e], dst = ei[NE + e];
        float ssum = sc;
        ssum += __shfl_xor(ssum, 1);
        ssum += __shfl_xor(ssum, 2);
        ssum += __shfl_xor(ssum, 4);
        float s = ssum * inv_sqrt8;
        s = fminf(fmaxf(s, -CLAMP_V), CLAMP_V);
        float ex = __expf(s);
        int h = lane >> 3;
        float alpha = ex / (den[dst * 8 + h] + 1e-16f);
        float val = alpha * (V[(size_t)src*64 + lane] + sc);
        atomicAdd(&wV[(size_t)dst * 64 + lane], val);
    }
}

extern "C" void kernel_launch(void* const* d_in, const int* in_sizes, int n_in,
                              void* d_out, int out_size, void* d_ws, size_t ws_size,
                              hipStream_t stream) {
    const float* x         = (const float*)d_in[0];
    const float* edge_attr = (const float*)d_in[1];
    const float* WQ        = (const float*)d_in[2];
    const float* bQ        = (const float*)d_in[3];
    const float* WK        = (const float*)d_in[4];
    const float* WVw       = (const float*)d_in[5];
    const float* WE1       = (const float*)d_in[6];
    const float* bE1       = (const float*)d_in[7];
    const int*   ei        = (const int*)d_in[8];

    float* out = (float*)d_out;
    float* wV = out;                          // [NN, 64]
    float* wE = out + (size_t)NN * 64;        // [NE, 64]

    float* Q   = (float*)d_ws;                // [NN,64]
    float* K   = Q + (size_t)NN * 64;         // [NN,64]
    float* V   = K + (size_t)NN * 64;         // [NN,64]
    float* den = V + (size_t)NN * 64;         // [NN,8]

    hipMemsetAsync(wV,  0, (size_t)NN * 64 * sizeof(float), stream);
    hipMemsetAsync(den, 0, (size_t)NN * 8  * sizeof(float), stream);

    proj_kernel<<<2048, 256, 0, stream>>>(x, WQ, bQ, WK, WVw, Q, K, V);
    edge_kernel<<<2048, 256, 0, stream>>>(edge_attr, WE1, bE1, ei, Q, K, wE, den);
    agg_kernel<<<2048, 256, 0, stream>>>(wE, ei, V, den, wV);
}

// Round 2
// 845.795 us; speedup vs baseline: 1.8138x; 1.8138x over previous
//
#include <hip/hip_runtime.h>

#define NN 50000
#define NE 1600000
#define CLAMP_V 5.0f

typedef __attribute__((ext_vector_type(4))) short bf16x4;
typedef __attribute__((ext_vector_type(4))) float f32x4;

static __device__ __forceinline__ short f2bf(float x) {
    unsigned u = __builtin_bit_cast(unsigned, x);
    u += 0x7FFF + ((u >> 16) & 1);   // round-to-nearest-even
    return (short)(u >> 16);
}

__global__ __launch_bounds__(256) void proj_kernel(
    const float* __restrict__ x,
    const float* __restrict__ WQ, const float* __restrict__ bQ,
    const float* __restrict__ WK, const float* __restrict__ WVw,
    float* __restrict__ Q, float* __restrict__ K, float* __restrict__ V)
{
    __shared__ float sWQ[4096], sWK[4096], sWV[4096];
    for (int i = threadIdx.x; i < 4096; i += 256) {
        sWQ[i] = WQ[i]; sWK[i] = WK[i]; sWV[i] = WVw[i];
    }
    __syncthreads();
    const int col = threadIdx.x & 63;
    const int nl  = threadIdx.x >> 6;
    const float bq = bQ[col];
    for (int node = blockIdx.x * 4 + nl; node < NN; node += gridDim.x * 4) {
        const float* xr = x + (size_t)node * 64;
        float aq = 0.f, ak = 0.f, av = 0.f;
        #pragma unroll
        for (int j = 0; j < 64; ++j) {
            float xv = xr[j];
            aq = fmaf(xv, sWQ[j*64+col], aq);
            ak = fmaf(xv, sWK[j*64+col], ak);
            av = fmaf(xv, sWV[j*64+col], av);
        }
        Q[(size_t)node*64+col] = aq + bq;
        K[(size_t)node*64+col] = ak;
        V[(size_t)node*64+col] = av;
    }
}

// Fused: E = edge_attr @ WE1 + bE1 via MFMA (16 edges per wave per tile),
// then score = K[src]*Q[dst]*E, wE write, per-head exp-sum into den.
__global__ __launch_bounds__(256) void edge_fused_kernel(
    const float* __restrict__ edge_attr,
    const float* __restrict__ WE1, const float* __restrict__ bE1,
    const int* __restrict__ ei,
    const float* __restrict__ Q, const float* __restrict__ K,
    float* __restrict__ wE, float* __restrict__ den)
{
    __shared__ float Elds[4][16 * 65];   // per-wave 16x64 tile, pad 65 (read side conflict-free)
    const int tid  = threadIdx.x;
    const int wv   = tid >> 6;
    const int lane = tid & 63;
    const int g    = lane >> 4;      // k-group 0..3
    const int rowl = lane & 15;      // A-row / B-col within 16

    // One-time: B fragments of WE1 (bf16) + bias. B[k=(ks*16 + g*4 + j)][col]
    bf16x4 bF[4][4];   // [colblock][kstep]
    float  bias[4];
    #pragma unroll
    for (int cb = 0; cb < 4; ++cb) {
        const int col = rowl + 16 * cb;
        bias[cb] = bE1[col];
        #pragma unroll
        for (int ks = 0; ks < 4; ++ks) {
            bf16x4 t;
            #pragma unroll
            for (int j = 0; j < 4; ++j)
                t[j] = f2bf(WE1[(ks * 16 + g * 4 + j) * 64 + col]);
            bF[cb][ks] = t;
        }
    }

    const float inv_sqrt8 = 0.35355339059327373f;

    for (int tile = blockIdx.x; tile < (NE / 64); tile += gridDim.x) {
        const int eBase = tile * 64 + wv * 16;   // this wave's 16 edges

        // A fragments: edge_attr[eBase+rowl][ks*16 + g*4 + j]  (float4 loads)
        bf16x4 aF[4];
        const float* ar = edge_attr + (size_t)(eBase + rowl) * 64 + g * 4;
        #pragma unroll
        for (int ks = 0; ks < 4; ++ks) {
            f32x4 v = *reinterpret_cast<const f32x4*>(ar + ks * 16);
            bf16x4 t;
            #pragma unroll
            for (int j = 0; j < 4; ++j) t[j] = f2bf(v[j]);
            aF[ks] = t;
        }

        // E tile: 4 col-blocks x 4 K-steps of 16x16x16 bf16 MFMA
        f32x4 acc[4];
        #pragma unroll
        for (int cb = 0; cb < 4; ++cb) {
            acc[cb][0] = bias[cb]; acc[cb][1] = bias[cb];
            acc[cb][2] = bias[cb]; acc[cb][3] = bias[cb];
        }
        #pragma unroll
        for (int cb = 0; cb < 4; ++cb)
            #pragma unroll
            for (int ks = 0; ks < 4; ++ks)
                acc[cb] = __builtin_amdgcn_mfma_f32_16x16x16bf16_1k(
                    aF[ks], bF[cb][ks], acc[cb], 0, 0, 0);

        // D layout: row=(lane>>4)*4+r, col=(lane&15)+16*cb  -> LDS transpose
        #pragma unroll
        for (int cb = 0; cb < 4; ++cb)
            #pragma unroll
            for (int r = 0; r < 4; ++r)
                Elds[wv][(g * 4 + r) * 65 + rowl + 16 * cb] = acc[cb][r];
        // same-wave LDS ordering: compiler inserts lgkmcnt waits; no barrier needed

        // Scoring: lane = column, one edge at a time (coalesced 256B gathers)
        #pragma unroll 2
        for (int el = 0; el < 16; ++el) {
            const int e   = eBase + el;
            const int src = ei[e];
            const int dst = ei[NE + e];
            const float El = Elds[wv][el * 65 + lane];
            const float sc = K[(size_t)src * 64 + lane] * Q[(size_t)dst * 64 + lane] * El;
            wE[(size_t)e * 64 + lane] = sc;
            float ss = sc;
            ss += __shfl_xor(ss, 1);
            ss += __shfl_xor(ss, 2);
            ss += __shfl_xor(ss, 4);
            float s = fminf(fmaxf(ss * inv_sqrt8, -CLAMP_V), CLAMP_V);
            float ex = __expf(s);
            if ((lane & 7) == 0)
                atomicAdd(&den[dst * 8 + (lane >> 3)], ex);
        }
    }
}

__global__ __launch_bounds__(256) void agg_kernel(
    const float* __restrict__ wE,
    const int* __restrict__ ei,
    const float* __restrict__ V,
    const float* __restrict__ den,
    float* __restrict__ wV)
{
    const int lane   = threadIdx.x & 63;
    const int waveId = (blockIdx.x * 256 + threadIdx.x) >> 6;
    const int nWaves = (gridDim.x * 256) >> 6;
    const float inv_sqrt8 = 0.35355339059327373f;
    for (int e = waveId; e < NE; e += nWaves) {
        float sc = wE[(size_t)e * 64 + lane];
        int src = ei[e], dst = ei[NE + e];
        float ss = sc;
        ss += __shfl_xor(ss, 1);
        ss += __shfl_xor(ss, 2);
        ss += __shfl_xor(ss, 4);
        float s = fminf(fmaxf(ss * inv_sqrt8, -CLAMP_V), CLAMP_V);
        float ex = __expf(s);
        int h = lane >> 3;
        float alpha = ex / (den[dst * 8 + h] + 1e-16f);
        float val = alpha * (V[(size_t)src * 64 + lane] + sc);
        atomicAdd(&wV[(size_t)dst * 64 + lane], val);
    }
}

extern "C" void kernel_launch(void* const* d_in, const int* in_sizes, int n_in,
                              void* d_out, int out_size, void* d_ws, size_t ws_size,
                              hipStream_t stream) {
    const float* x         = (const float*)d_in[0];
    const float* edge_attr = (const float*)d_in[1];
    const float* WQ        = (const float*)d_in[2];
    const float* bQ        = (const float*)d_in[3];
    const float* WK        = (const float*)d_in[4];
    const float* WVw       = (const float*)d_in[5];
    const float* WE1       = (const float*)d_in[6];
    const float* bE1       = (const float*)d_in[7];
    const int*   ei        = (const int*)d_in[8];

    float* out = (float*)d_out;
    float* wV = out;                          // [NN, 64]
    float* wE = out + (size_t)NN * 64;        // [NE, 64]

    float* Q   = (float*)d_ws;                // [NN,64]
    float* K   = Q + (size_t)NN * 64;         // [NN,64]
    float* V   = K + (size_t)NN * 64;         // [NN,64]
    float* den = V + (size_t)NN * 64;         // [NN,8]

    hipMemsetAsync(wV,  0, (size_t)NN * 64 * sizeof(float), stream);
    hipMemsetAsync(den, 0, (size_t)NN * 8  * sizeof(float), stream);

    proj_kernel<<<2048, 256, 0, stream>>>(x, WQ, bQ, WK, WVw, Q, K, V);
    edge_fused_kernel<<<2048, 256, 0, stream>>>(edge_attr, WE1, bE1, ei, Q, K, wE, den);
    agg_kernel<<<2048, 256, 0, stream>>>(wE, ei, V, den, wV);
}

// Round 3
// 701.863 us; speedup vs baseline: 2.1857x; 1.2051x over previous
//
#include <hip/hip_runtime.h>

#define NN 50000
#define NE 1600000
#define CLAMP_V 5.0f

typedef __attribute__((ext_vector_type(4))) short bf16x4;
typedef __attribute__((ext_vector_type(4))) float f32x4;

static __device__ __forceinline__ short f2bf(float x) {
    unsigned u = __builtin_bit_cast(unsigned, x);
    u += 0x7FFF + ((u >> 16) & 1);   // round-to-nearest-even
    return (short)(u >> 16);
}

__global__ __launch_bounds__(256) void proj_kernel(
    const float* __restrict__ x,
    const float* __restrict__ WQ, const float* __restrict__ bQ,
    const float* __restrict__ WK, const float* __restrict__ WVw,
    float* __restrict__ Q, float* __restrict__ K, float* __restrict__ V)
{
    __shared__ float sWQ[4096], sWK[4096], sWV[4096];
    for (int i = threadIdx.x; i < 4096; i += 256) {
        sWQ[i] = WQ[i]; sWK[i] = WK[i]; sWV[i] = WVw[i];
    }
    __syncthreads();
    const int col = threadIdx.x & 63;
    const int nl  = threadIdx.x >> 6;
    const float bq = bQ[col];
    for (int node = blockIdx.x * 4 + nl; node < NN; node += gridDim.x * 4) {
        const float* xr = x + (size_t)node * 64;
        float aq = 0.f, ak = 0.f, av = 0.f;
        #pragma unroll
        for (int j = 0; j < 64; ++j) {
            float xv = xr[j];
            aq = fmaf(xv, sWQ[j*64+col], aq);
            ak = fmaf(xv, sWK[j*64+col], ak);
            av = fmaf(xv, sWV[j*64+col], av);
        }
        Q[(size_t)node*64+col] = aq + bq;
        K[(size_t)node*64+col] = ak;
        V[(size_t)node*64+col] = av;
    }
}

// Fully fused edge pass:
//  E = edge_attr @ WE1 + bE1 (MFMA), sc = K[src]*Q[dst]*E -> wE,
//  ex = exp(clamp(sum_head(sc)/sqrt8)), den[dst,h] += ex (atomic),
//  Num[dst,c] += ex*(V[src,c]+sc)      (atomic)   -- division deferred
__global__ __launch_bounds__(256) void edge_fused_kernel(
    const float* __restrict__ edge_attr,
    const float* __restrict__ WE1, const float* __restrict__ bE1,
    const int* __restrict__ ei,
    const float* __restrict__ Q, const float* __restrict__ K,
    const float* __restrict__ V,
    float* __restrict__ wE, float* __restrict__ den, float* __restrict__ Num)
{
    __shared__ float Elds[4][16 * 65];   // per-wave 16x64 tile, padded
    const int tid  = threadIdx.x;
    const int wv   = tid >> 6;
    const int lane = tid & 63;
    const int g    = lane >> 4;      // k-group 0..3
    const int rowl = lane & 15;      // A-row / B-col within 16

    // B fragments of WE1 (bf16) + bias. B[k=(ks*16 + g*4 + j)][col]
    bf16x4 bF[4][4];
    float  bias[4];
    #pragma unroll
    for (int cb = 0; cb < 4; ++cb) {
        const int col = rowl + 16 * cb;
        bias[cb] = bE1[col];
        #pragma unroll
        for (int ks = 0; ks < 4; ++ks) {
            bf16x4 t;
            #pragma unroll
            for (int j = 0; j < 4; ++j)
                t[j] = f2bf(WE1[(ks * 16 + g * 4 + j) * 64 + col]);
            bF[cb][ks] = t;
        }
    }

    const float inv_sqrt8 = 0.35355339059327373f;

    for (int tile = blockIdx.x; tile < (NE / 64); tile += gridDim.x) {
        const int eBase = tile * 64 + wv * 16;

        bf16x4 aF[4];
        const float* ar = edge_attr + (size_t)(eBase + rowl) * 64 + g * 4;
        #pragma unroll
        for (int ks = 0; ks < 4; ++ks) {
            f32x4 v = *reinterpret_cast<const f32x4*>(ar + ks * 16);
            bf16x4 t;
            #pragma unroll
            for (int j = 0; j < 4; ++j) t[j] = f2bf(v[j]);
            aF[ks] = t;
        }

        f32x4 acc[4];
        #pragma unroll
        for (int cb = 0; cb < 4; ++cb) {
            acc[cb][0] = bias[cb]; acc[cb][1] = bias[cb];
            acc[cb][2] = bias[cb]; acc[cb][3] = bias[cb];
        }
        #pragma unroll
        for (int cb = 0; cb < 4; ++cb)
            #pragma unroll
            for (int ks = 0; ks < 4; ++ks)
                acc[cb] = __builtin_amdgcn_mfma_f32_16x16x16bf16_1k(
                    aF[ks], bF[cb][ks], acc[cb], 0, 0, 0);

        // D layout: row=(lane>>4)*4+r, col=(lane&15)+16*cb  -> LDS transpose
        #pragma unroll
        for (int cb = 0; cb < 4; ++cb)
            #pragma unroll
            for (int r = 0; r < 4; ++r)
                Elds[wv][(g * 4 + r) * 65 + rowl + 16 * cb] = acc[cb][r];

        // Scoring + aggregation: lane = column, 4 edges per unrolled group
        #pragma unroll 4
        for (int el = 0; el < 16; ++el) {
            const int e   = eBase + el;
            const int src = ei[e];
            const int dst = ei[NE + e];
            const float Kv = K[(size_t)src * 64 + lane];
            const float Qv = Q[(size_t)dst * 64 + lane];
            const float Vv = V[(size_t)src * 64 + lane];
            const float El = Elds[wv][el * 65 + lane];
            const float sc = Kv * Qv * El;
            wE[(size_t)e * 64 + lane] = sc;
            float ss = sc;
            ss += __shfl_xor(ss, 1);
            ss += __shfl_xor(ss, 2);
            ss += __shfl_xor(ss, 4);
            float s = fminf(fmaxf(ss * inv_sqrt8, -CLAMP_V), CLAMP_V);
            float ex = __expf(s);
            if ((lane & 7) == 0)
                atomicAdd(&den[dst * 8 + (lane >> 3)], ex);
            atomicAdd(&Num[(size_t)dst * 64 + lane], ex * (Vv + sc));
        }
    }
}

__global__ __launch_bounds__(256) void finalize_kernel(
    const float* __restrict__ Num, const float* __restrict__ den,
    float* __restrict__ wV)
{
    const int i = blockIdx.x * 256 + threadIdx.x;   // one float4 per thread
    if (i >= NN * 16) return;
    const int c4 = i & 15;            // which float4 within the row
    const int n  = i >> 4;
    const int h  = c4 >> 1;           // head = (c4*4)>>3
    const float d = den[n * 8 + h] + 1e-16f;
    f32x4 v = reinterpret_cast<const f32x4*>(Num)[i];
    v[0] /= d; v[1] /= d; v[2] /= d; v[3] /= d;
    reinterpret_cast<f32x4*>(wV)[i] = v;
}

extern "C" void kernel_launch(void* const* d_in, const int* in_sizes, int n_in,
                              void* d_out, int out_size, void* d_ws, size_t ws_size,
                              hipStream_t stream) {
    const float* x         = (const float*)d_in[0];
    const float* edge_attr = (const float*)d_in[1];
    const float* WQ        = (const float*)d_in[2];
    const float* bQ        = (const float*)d_in[3];
    const float* WK        = (const float*)d_in[4];
    const float* WVw       = (const float*)d_in[5];
    const float* WE1       = (const float*)d_in[6];
    const float* bE1       = (const float*)d_in[7];
    const int*   ei        = (const int*)d_in[8];

    float* out = (float*)d_out;
    float* wV = out;                          // [NN, 64]
    float* wE = out + (size_t)NN * 64;        // [NE, 64]

    float* Q   = (float*)d_ws;                // [NN,64]
    float* K   = Q + (size_t)NN * 64;         // [NN,64]
    float* V   = K + (size_t)NN * 64;         // [NN,64]
    float* den = V + (size_t)NN * 64;         // [NN,8]
    float* Num = den + (size_t)NN * 8;        // [NN,64]

    hipMemsetAsync(den, 0, (size_t)NN * 8  * sizeof(float), stream);
    hipMemsetAsync(Num, 0, (size_t)NN * 64 * sizeof(float), stream);

    proj_kernel<<<2048, 256, 0, stream>>>(x, WQ, bQ, WK, WVw, Q, K, V);
    edge_fused_kernel<<<2048, 256, 0, stream>>>(edge_attr, WE1, bE1, ei, Q, K, V,
                                                wE, den, Num);
    finalize_kernel<<<(NN * 16 + 255) / 256, 256, 0, stream>>>(Num, den, wV);
}